// Round 7
// baseline (623.440 us; speedup 1.0000x reference)
//
#include <hip/hip_runtime.h>
#include <math.h>

#define SCALE_ 0.125f

typedef _Float16 half_t;
typedef __attribute__((ext_vector_type(8))) _Float16 f16x8;
typedef __attribute__((ext_vector_type(4))) _Float16 f16x4;
typedef __attribute__((ext_vector_type(4))) float f32x4;

#define AS1 __attribute__((address_space(1)))
#define AS3 __attribute__((address_space(3)))

__device__ __forceinline__ f32x4 mfma16(f16x8 a, f16x8 b, f32x4 c) {
  return __builtin_amdgcn_mfma_f32_16x16x32_f16(a, b, c, 0, 0, 0);
}
__device__ __forceinline__ void gload16(const void* g, void* l) {
  __builtin_amdgcn_global_load_lds((const AS1 void*)g, (AS3 void*)l, 16, 0, 0);
}
// split f into fp16 hi + fp16 lo (residual); hi+lo ~ 2^-22 relative accuracy
__device__ __forceinline__ void split2(float f, half_t* h, half_t* l) {
  half_t hh = (half_t)f;
  *h = hh;
  *l = (half_t)(f - (float)hh);
}

// ---------------------------------------------------------------------------
// Convert+transpose 6 weight mats: fp32 [K=1024][N=1024] -> fp16 hi/lo [N][K]
// ---------------------------------------------------------------------------
__global__ __launch_bounds__(256) void convw_kernel(
    const float* __restrict__ W0, const float* __restrict__ W1,
    const float* __restrict__ W2, const float* __restrict__ W3,
    const float* __restrict__ W4, const float* __restrict__ W5,
    half_t* __restrict__ wh, half_t* __restrict__ wl)
{
  const int z = blockIdx.z;
  const float* W = (z == 0) ? W0 : (z == 1) ? W1 : (z == 2) ? W2
                  : (z == 3) ? W3 : (z == 4) ? W4 : W5;
  half_t* outh = wh + z * 1048576;
  half_t* outl = wl + z * 1048576;
  const int n0 = blockIdx.x * 32, k0 = blockIdx.y * 32;
  const int t = threadIdx.x, r = t >> 3, c4 = (t & 7) * 4;
  __shared__ float lds[32][33];
  float4 v = *(const float4*)&W[(k0 + r) * 1024 + n0 + c4];
  lds[r][c4 + 0] = v.x; lds[r][c4 + 1] = v.y;
  lds[r][c4 + 2] = v.z; lds[r][c4 + 3] = v.w;
  __syncthreads();
  f16x4 oh, ol;
#pragma unroll
  for (int j = 0; j < 4; ++j) {
    const float f = lds[c4 + j][r];
    half_t hv, lv; split2(f, &hv, &lv);
    oh[j] = hv; ol[j] = lv;
  }
  *(f16x4*)&outh[(n0 + r) * 1024 + k0 + c4] = oh;
  *(f16x4*)&outl[(n0 + r) * 1024 + k0 + c4] = ol;
}

// ---------------------------------------------------------------------------
// x fp32 [4096][1024] -> fp16 hi/lo (same layout)
// ---------------------------------------------------------------------------
__global__ __launch_bounds__(256) void convx_kernel(
    const float* __restrict__ x, half_t* __restrict__ xh, half_t* __restrict__ xl)
{
  const int i = (blockIdx.x * 256 + threadIdx.x) * 4;
  float4 v = *(const float4*)&x[i];
  float vv[4] = {v.x, v.y, v.z, v.w};
  f16x4 oh, ol;
#pragma unroll
  for (int j = 0; j < 4; ++j) {
    half_t hv, lv; split2(vv[j], &hv, &lv);
    oh[j] = hv; ol[j] = lv;
  }
  *(f16x4*)&xh[i] = oh;
  *(f16x4*)&xl[i] = ol;
}

// ---------------------------------------------------------------------------
// Split-fp16 MFMA GEMM, m97 structure: 128x128 tile, BK=32, 4 waves (2x2),
// global_load_lds w=16, 3-term (AhBh + AhBl + AlBh).
// proj mode z: 0=Wq_re 1=Wq_im 2=Wk_re 3=Wk_im (fp16-split into qt/kt at
// remapped cols [h*128 + d (+64 for im)]), 4=Wv (written transposed, hi only
// consumed by attn; lo kept for numerics of nothing else -> skip lo store).
// final_mode: A=abuf, B=Wo (widx 5), out fp32.
// ---------------------------------------------------------------------------
__global__ __launch_bounds__(256) void gemm_kernel(
    const half_t* __restrict__ Agh, const half_t* __restrict__ Agl,
    const half_t* __restrict__ wh, const half_t* __restrict__ wl,
    half_t* __restrict__ qth, half_t* __restrict__ qtl,
    half_t* __restrict__ kth, half_t* __restrict__ ktl,
    half_t* __restrict__ vTh, half_t* __restrict__ vTl,
    float* __restrict__ outp, int final_mode)
{
  __shared__ half_t Ash[4096], Asl[4096], Bsh[4096], Bsl[4096];  // 4x8KB
  const int z = blockIdx.z;
  const int widx = final_mode ? 5 : z;
  const half_t* Bth = wh + widx * 1048576;
  const half_t* Btl = wl + widx * 1048576;

  const int n0 = blockIdx.x * 128, m0 = blockIdx.y * 128;
  const int tid = threadIdx.x, lane = tid & 63, wid = tid >> 6;
  const int wr = wid >> 1, wc = wid & 1, l15 = lane & 15, l4 = lane >> 4;

  f32x4 acc[4][4];
#pragma unroll
  for (int i = 0; i < 4; ++i)
#pragma unroll
    for (int j = 0; j < 4; ++j) acc[i][j] = (f32x4){0.f, 0.f, 0.f, 0.f};

  // staging: tile = 512 16B-slots; slot s -> row s>>2, halfcol (s&3)*8
  const int s0 = wid * 64 + lane, s1 = s0 + 256;
  const int r0 = s0 >> 2, c0 = (s0 & 3) * 8;
  const int r1 = s1 >> 2, c1 = (s1 & 3) * 8;
  half_t* Ah0 = Ash + wid * 512;        half_t* Ah1 = Ash + 2048 + wid * 512;
  half_t* Al0 = Asl + wid * 512;        half_t* Al1 = Asl + 2048 + wid * 512;
  half_t* Bh0 = Bsh + wid * 512;        half_t* Bh1 = Bsh + 2048 + wid * 512;
  half_t* Bl0 = Bsl + wid * 512;        half_t* Bl1 = Bsl + 2048 + wid * 512;

  for (int k0 = 0; k0 < 1024; k0 += 32) {
    __syncthreads();
    gload16(Agh + (m0 + r0) * 1024 + k0 + c0, Ah0);
    gload16(Agh + (m0 + r1) * 1024 + k0 + c1, Ah1);
    gload16(Agl + (m0 + r0) * 1024 + k0 + c0, Al0);
    gload16(Agl + (m0 + r1) * 1024 + k0 + c1, Al1);
    gload16(Bth + (n0 + r0) * 1024 + k0 + c0, Bh0);
    gload16(Bth + (n0 + r1) * 1024 + k0 + c1, Bh1);
    gload16(Btl + (n0 + r0) * 1024 + k0 + c0, Bl0);
    gload16(Btl + (n0 + r1) * 1024 + k0 + c1, Bl1);
    __syncthreads();
    f16x8 ah[4], al[4], bh[4], bl[4];
#pragma unroll
    for (int i = 0; i < 4; ++i) {
      const int ro = (wr * 64 + i * 16 + l15) * 32 + l4 * 8;
      ah[i] = *(const f16x8*)&Ash[ro];
      al[i] = *(const f16x8*)&Asl[ro];
    }
#pragma unroll
    for (int j = 0; j < 4; ++j) {
      const int ro = (wc * 64 + j * 16 + l15) * 32 + l4 * 8;
      bh[j] = *(const f16x8*)&Bsh[ro];
      bl[j] = *(const f16x8*)&Bsl[ro];
    }
#pragma unroll
    for (int i = 0; i < 4; ++i)
#pragma unroll
      for (int j = 0; j < 4; ++j) {
        acc[i][j] = mfma16(ah[i], bh[j], acc[i][j]);
        acc[i][j] = mfma16(ah[i], bl[j], acc[i][j]);
        acc[i][j] = mfma16(al[i], bh[j], acc[i][j]);
      }
  }

#pragma unroll
  for (int i = 0; i < 4; ++i) {
    const int mb = m0 + wr * 64 + i * 16 + l4 * 4;
#pragma unroll
    for (int j = 0; j < 4; ++j) {
      const int n = n0 + wc * 64 + j * 16 + l15;
      if (final_mode) {
#pragma unroll
        for (int r = 0; r < 4; ++r) outp[(mb + r) * 1024 + n] = acc[i][j][r];
      } else if (z < 4) {
        half_t* dh = (z < 2) ? qth : kth;
        half_t* dl = (z < 2) ? qtl : ktl;
        const int colr = (n >> 6) * 128 + (n & 63) + ((z & 1) ? 64 : 0);
#pragma unroll
        for (int r = 0; r < 4; ++r) {
          half_t hv, lv; split2(acc[i][j][r], &hv, &lv);
          dh[(mb + r) * 2048 + colr] = hv;
          dl[(mb + r) * 2048 + colr] = lv;
        }
      } else {  // V: write transposed hi, [bh][d][t], r -> contiguous t
        const int hh = n >> 6, d = n & 63;
        const int bq = mb >> 11, t = mb & 2047;
        f16x4 vh4;
#pragma unroll
        for (int r = 0; r < 4; ++r) vh4[r] = (half_t)acc[i][j][r];
        const int off = ((bq * 16 + hh) * 64 + d) * 2048 + t;
        *(f16x4*)&vTh[off] = vh4;
      }
    }
  }
}

// ---------------------------------------------------------------------------
// RoPE: reconstruct fp32 from hi+lo, rotate, re-split to qb/kb [bh][t][128]
// (re|im), q pre-scaled by SCALE. One 64-lane wave per (m,h).
// ---------------------------------------------------------------------------
__global__ __launch_bounds__(256) void rope_kernel(
    const half_t* __restrict__ qth, const half_t* __restrict__ qtl,
    const half_t* __restrict__ kth, const half_t* __restrict__ ktl,
    const float* __restrict__ cosb, const float* __restrict__ sinb,
    half_t* __restrict__ qbh, half_t* __restrict__ qbl,
    half_t* __restrict__ kbh, half_t* __restrict__ kbl)
{
  const int z = blockIdx.y;
  const int g = blockIdx.x * 4 + (threadIdx.x >> 6);
  const int d = threadIdx.x & 63;
  const int m = g >> 4, h = g & 15;
  const int b = m >> 11, t = m & 2047;
  const half_t* sh = (z ? kth : qth) + m * 2048 + h * 128;
  const half_t* sl = (z ? ktl : qtl) + m * 2048 + h * 128;
  const float re = (float)sh[d] + (float)sl[d];
  const float im = (float)sh[64 + d] + (float)sl[64 + d];
  const float c = cosb[t * 64 + d], s = sinb[t * 64 + d];
  float rer = re * c - im * s;
  float imr = re * s + im * c;
  if (z == 0) { rer *= SCALE_; imr *= SCALE_; }
  half_t* dh = (z ? kbh : qbh) + ((b * 16 + h) * 2048 + t) * 128;
  half_t* dl = (z ? kbl : qbl) + ((b * 16 + h) * 2048 + t) * 128;
  half_t hv, lv;
  split2(rer, &hv, &lv); dh[d] = hv;      dl[d] = lv;
  split2(imr, &hv, &lv); dh[64 + d] = hv; dl[64 + d] = lv;
}

// ---------------------------------------------------------------------------
// Flash attention, split-fp16 MFMA, BARRIER-FREE.
// 256 thr (4 waves); QB=64 (wave w owns q-rows q0+w*16..+15); KB=64.
// K (hi+lo) and V (hi) are read DIRECTLY from global per MFMA fragment
// (L2-resident: 53 MB FETCH at round 6 proves cache residency; m169 lesson).
// Only P goes through LDS (wave-private transpose; pitch 80 + XOR swizzle).
// No __syncthreads anywhere; waves run fully independently.
// Grid 1024: bh = i&31 (bh -> fixed XCD for L2 locality);
// qt = i<512 ? 31-(i>>5) : (i>>5)-16 (paired sums: per-CU Sum(qt) == 62).
// QK^T: 3-term split (qh*kh + qh*kl + ql*kh). PV: hi-only (P,V fp16).
// ---------------------------------------------------------------------------
__global__ __launch_bounds__(256) void attn_kernel(
    const half_t* __restrict__ qbh, const half_t* __restrict__ qbl,
    const half_t* __restrict__ kbh, const half_t* __restrict__ kbl,
    const half_t* __restrict__ vTh,
    half_t* __restrict__ abh, half_t* __restrict__ abl)
{
  const int i = blockIdx.x;
  const int bh = i & 31;
  const int j = i >> 5;                       // 0..31
  const int qt = (i < 512) ? (31 - j) : (j - 16);
  const int b = bh >> 4, h = bh & 15;
  const int tid = threadIdx.x, lane = tid & 63, w = tid >> 6;
  const int l15 = lane & 15, l4 = lane >> 4;
  const int q0 = qt * 64;

  __shared__ half_t Ph[64 * 80];  // P hi, pitch 80 halves, XOR-swizzled slots

  // Q fragments (hi/lo), rows q0 + w*16 + l15
  f16x8 qh[4], ql[4];
  {
    const size_t qoff = ((size_t)bh * 2048 + q0 + w * 16 + l15) * 128;
#pragma unroll
    for (int c = 0; c < 4; ++c) {
      qh[c] = *(const f16x8*)(qbh + qoff + c * 32 + l4 * 8);
      ql[c] = *(const f16x8*)(qbl + qoff + c * 32 + l4 * 8);
    }
  }

  f32x4 o[4];
#pragma unroll
  for (int n = 0; n < 4; ++n) o[n] = (f32x4){0.f, 0.f, 0.f, 0.f};
  float mrow[4] = {-3e38f, -3e38f, -3e38f, -3e38f};
  float lrow[4] = {0.f, 0.f, 0.f, 0.f};

  const half_t* kh_p = kbh + (size_t)bh * 2048 * 128;
  const half_t* kl_p = kbl + (size_t)bh * 2048 * 128;
  const half_t* vh_p = vTh + (size_t)bh * 64 * 2048;

  const int qminw = q0 + w * 16;              // wave's first q-row
  const int qmaxw = qminw + 15;               // wave's last q-row

  for (int kt = 0; kt <= qt; ++kt) {
    const int k0 = kt * 64;
    const bool diag = (kt == qt);

    // S = Q K^T over KB=64 (4 n-subtiles of 16 k-cols), direct-global K frags
    f32x4 s[4];
#pragma unroll
    for (int n = 0; n < 4; ++n) s[n] = (f32x4){0.f, 0.f, 0.f, 0.f};
#pragma unroll
    for (int n = 0; n < 4; ++n) {
      if (diag && k0 + n * 16 > qmaxw) continue;  // fully-masked subtile
      const half_t* kp  = kh_p + (size_t)(k0 + n * 16 + l15) * 128 + l4 * 8;
      const half_t* klp = kl_p + (size_t)(k0 + n * 16 + l15) * 128 + l4 * 8;
#pragma unroll
      for (int c = 0; c < 4; ++c) {
        const f16x8 kfh = *(const f16x8*)(kp + c * 32);
        const f16x8 kfl = *(const f16x8*)(klp + c * 32);
        s[n] = mfma16(qh[c], kfh, s[n]);
        s[n] = mfma16(qh[c], kfl, s[n]);
        s[n] = mfma16(ql[c], kfh, s[n]);
      }
    }

    if (diag) {  // elementwise causal mask (covers skipped subtiles too)
#pragma unroll
      for (int n = 0; n < 4; ++n)
#pragma unroll
        for (int r = 0; r < 4; ++r)
          if (k0 + n * 16 + l15 > qminw + l4 * 4 + r) s[n][r] = -3e38f;
    }

    // online softmax (row = (l4,r); row group = 16 contiguous lanes)
#pragma unroll
    for (int r = 0; r < 4; ++r) {
      float mx = fmaxf(fmaxf(s[0][r], s[1][r]), fmaxf(s[2][r], s[3][r]));
      mx = fmaxf(mx, __shfl_xor(mx, 1));
      mx = fmaxf(mx, __shfl_xor(mx, 2));
      mx = fmaxf(mx, __shfl_xor(mx, 4));
      mx = fmaxf(mx, __shfl_xor(mx, 8));
      const float mnew = fmaxf(mrow[r], mx);
      const float alpha = __expf(mrow[r] - mnew);
      float p[4];
#pragma unroll
      for (int n = 0; n < 4; ++n) p[n] = __expf(s[n][r] - mnew);
      float rs = p[0] + p[1] + p[2] + p[3];
      rs += __shfl_xor(rs, 1);
      rs += __shfl_xor(rs, 2);
      rs += __shfl_xor(rs, 4);
      rs += __shfl_xor(rs, 8);
      lrow[r] = lrow[r] * alpha + rs;
      mrow[r] = mnew;
#pragma unroll
      for (int n = 0; n < 4; ++n) o[n][r] *= alpha;
      // write P row (hi only), swizzled: slot' = slot ^ (prow&7)
      const int prow = w * 16 + l4 * 4 + r;
      const int pr80 = prow * 80;
      const int psw = prow & 7;
#pragma unroll
      for (int n = 0; n < 4; ++n) {
        const int col = n * 16 + l15;
        const int sp = ((col >> 3) ^ psw) & 7;
        Ph[pr80 + sp * 8 + (col & 7)] = (half_t)p[n];
      }
    }

    // O += P V (P rows wave-private; V hi direct from global)
#pragma unroll
    for (int kc = 0; kc < 2; ++kc) {
      const int arow = w * 16 + l15;
      const int sp = ((kc * 4 + l4) ^ (arow & 7)) & 7;
      const f16x8 pf = *(const f16x8*)&Ph[arow * 80 + sp * 8];
#pragma unroll
      for (int n = 0; n < 4; ++n) {
        const f16x8 vf = *(const f16x8*)(vh_p + (size_t)(n * 16 + l15) * 2048 +
                                         k0 + kc * 32 + l4 * 8);
        o[n] = mfma16(pf, vf, o[n]);
      }
    }
  }

  const int mg = b * 2048 + q0 + w * 16 + l4 * 4;
#pragma unroll
  for (int r = 0; r < 4; ++r) {
    const float inv = 1.0f / lrow[r];
    const int m = mg + r;
#pragma unroll
    for (int n = 0; n < 4; ++n) {
      half_t hv, lv; split2(o[n][r] * inv, &hv, &lv);
      abh[m * 1024 + h * 64 + n * 16 + l15] = hv;
      abl[m * 1024 + h * 64 + n * 16 + l15] = lv;
    }
  }
}

// ---------------------------------------------------------------------------
extern "C" void kernel_launch(void* const* d_in, const int* in_sizes, int n_in,
                              void* d_out, int out_size, void* d_ws,
                              size_t ws_size, hipStream_t stream) {
  const float* x    = (const float*)d_in[0];
  const float* Wqre = (const float*)d_in[1];
  const float* Wqim = (const float*)d_in[2];
  const float* Wkre = (const float*)d_in[3];
  const float* Wkim = (const float*)d_in[4];
  const float* Wv   = (const float*)d_in[5];
  const float* Wo   = (const float*)d_in[6];
  const float* cosb = (const float*)d_in[7];
  const float* sinb = (const float*)d_in[8];

  char* w = (char*)d_ws;
  const size_t MB = (size_t)1 << 20;
  half_t* wh6 = (half_t*)(w + 0 * MB);    // 12 MB: 6x [1024][1024] fp16 hi
  half_t* wl6 = (half_t*)(w + 12 * MB);   // 12 MB: lo
  half_t* xh  = (half_t*)(w + 24 * MB);   // 8 MB
  half_t* xl  = (half_t*)(w + 32 * MB);   // 8 MB
  half_t* qth = (half_t*)(w + 40 * MB);   // 16 MB [4096][2048]
  half_t* qtl = (half_t*)(w + 56 * MB);   // 16 MB
  half_t* kth = (half_t*)(w + 72 * MB);   // 16 MB
  half_t* ktl = (half_t*)(w + 88 * MB);   // 16 MB
  half_t* qbh = (half_t*)(w + 104 * MB);  // 16 MB [32][2048][128]
  half_t* qbl = (half_t*)(w + 120 * MB);  // 16 MB
  half_t* kbh = (half_t*)(w + 136 * MB);  // 16 MB
  half_t* kbl = (half_t*)(w + 152 * MB);  // 16 MB
  half_t* vTh = (half_t*)(w + 168 * MB);  // 8 MB [32][64][2048]
  half_t* vTl = (half_t*)(w + 176 * MB);  // unused (kept for layout)
  // abuf aliases qth/qtl region (qtmp fully consumed by rope before attn)
  half_t* abh = (half_t*)(w + 40 * MB);   // 8 MB [4096][1024]
  half_t* abl = (half_t*)(w + 48 * MB);   // 8 MB

  dim3 blk(256);
  convw_kernel<<<dim3(32, 32, 6), blk, 0, stream>>>(Wqre, Wqim, Wkre, Wkim, Wv,
                                                    Wo, wh6, wl6);
  convx_kernel<<<dim3(4096), blk, 0, stream>>>(x, xh, xl);
  gemm_kernel<<<dim3(8, 32, 5), blk, 0, stream>>>(xh, xl, wh6, wl6, qth, qtl,
                                                  kth, ktl, vTh, vTl, nullptr, 0);
  rope_kernel<<<dim3(16384, 2), blk, 0, stream>>>(qth, qtl, kth, ktl, cosb,
                                                  sinb, qbh, qbl, kbh, kbl);
  attn_kernel<<<dim3(1024), blk, 0, stream>>>(qbh, qbl, kbh, kbl, vTh, abh,
                                              abl);
  gemm_kernel<<<dim3(8, 32, 1), blk, 0, stream>>>(abh, abl, wh6, wl6, nullptr,
                                                  nullptr, nullptr, nullptr,
                                                  nullptr, nullptr,
                                                  (float*)d_out, 1);
}

// Round 9
// 476.343 us; speedup vs baseline: 1.3088x; 1.3088x over previous
//
#include <hip/hip_runtime.h>
#include <math.h>

#define SCALE_ 0.125f

typedef _Float16 half_t;
typedef __attribute__((ext_vector_type(8))) _Float16 f16x8;
typedef __attribute__((ext_vector_type(4))) _Float16 f16x4;
typedef __attribute__((ext_vector_type(4))) float f32x4;

#define AS1 __attribute__((address_space(1)))
#define AS3 __attribute__((address_space(3)))

__device__ __forceinline__ f32x4 mfma16(f16x8 a, f16x8 b, f32x4 c) {
  return __builtin_amdgcn_mfma_f32_16x16x32_f16(a, b, c, 0, 0, 0);
}
__device__ __forceinline__ void gload16(const void* g, void* l) {
  __builtin_amdgcn_global_load_lds((const AS1 void*)g, (AS3 void*)l, 16, 0, 0);
}
// split f into fp16 hi + fp16 lo (residual); hi+lo ~ 2^-22 relative accuracy
__device__ __forceinline__ void split2(float f, half_t* h, half_t* l) {
  half_t hh = (half_t)f;
  *h = hh;
  *l = (half_t)(f - (float)hh);
}

// ---------------------------------------------------------------------------
// Convert+transpose 6 weight mats: fp32 [K=1024][N=1024] -> fp16 hi/lo [N][K]
// ---------------------------------------------------------------------------
__global__ __launch_bounds__(256) void convw_kernel(
    const float* __restrict__ W0, const float* __restrict__ W1,
    const float* __restrict__ W2, const float* __restrict__ W3,
    const float* __restrict__ W4, const float* __restrict__ W5,
    half_t* __restrict__ wh, half_t* __restrict__ wl)
{
  const int z = blockIdx.z;
  const float* W = (z == 0) ? W0 : (z == 1) ? W1 : (z == 2) ? W2
                  : (z == 3) ? W3 : (z == 4) ? W4 : W5;
  half_t* outh = wh + z * 1048576;
  half_t* outl = wl + z * 1048576;
  const int n0 = blockIdx.x * 32, k0 = blockIdx.y * 32;
  const int t = threadIdx.x, r = t >> 3, c4 = (t & 7) * 4;
  __shared__ float lds[32][33];
  float4 v = *(const float4*)&W[(k0 + r) * 1024 + n0 + c4];
  lds[r][c4 + 0] = v.x; lds[r][c4 + 1] = v.y;
  lds[r][c4 + 2] = v.z; lds[r][c4 + 3] = v.w;
  __syncthreads();
  f16x4 oh, ol;
#pragma unroll
  for (int j = 0; j < 4; ++j) {
    const float f = lds[c4 + j][r];
    half_t hv, lv; split2(f, &hv, &lv);
    oh[j] = hv; ol[j] = lv;
  }
  *(f16x4*)&outh[(n0 + r) * 1024 + k0 + c4] = oh;
  *(f16x4*)&outl[(n0 + r) * 1024 + k0 + c4] = ol;
}

// ---------------------------------------------------------------------------
// x fp32 [4096][1024] -> fp16 hi/lo (same layout)
// ---------------------------------------------------------------------------
__global__ __launch_bounds__(256) void convx_kernel(
    const float* __restrict__ x, half_t* __restrict__ xh, half_t* __restrict__ xl)
{
  const int i = (blockIdx.x * 256 + threadIdx.x) * 4;
  float4 v = *(const float4*)&x[i];
  float vv[4] = {v.x, v.y, v.z, v.w};
  f16x4 oh, ol;
#pragma unroll
  for (int j = 0; j < 4; ++j) {
    half_t hv, lv; split2(vv[j], &hv, &lv);
    oh[j] = hv; ol[j] = lv;
  }
  *(f16x4*)&xh[i] = oh;
  *(f16x4*)&xl[i] = ol;
}

// ---------------------------------------------------------------------------
// Fused projection + RoPE. z=0: q-pair (Wq_re,Wq_im); z=1: k-pair; z=2: V.
// Pair mode: dual accumulators (re,im) share the A (x) staging; epilogue
// applies the complex rotation with cos/sin and writes qb/kb hi/lo directly.
// V mode: 1-term (AhBh), transposed hi-only output [bh][d][t].
// 128x128 tile, BK=32, 4 waves (2x2), global_load_lds w=16, 3-term per acc.
// ---------------------------------------------------------------------------
__global__ __launch_bounds__(256) void proj_pair_kernel(
    const half_t* __restrict__ xh, const half_t* __restrict__ xl,
    const half_t* __restrict__ wh, const half_t* __restrict__ wl,
    const float* __restrict__ cosb, const float* __restrict__ sinb,
    half_t* __restrict__ qbh, half_t* __restrict__ qbl,
    half_t* __restrict__ kbh, half_t* __restrict__ kbl,
    half_t* __restrict__ vTh)
{
  __shared__ half_t Ash[4096], Asl[4096];
  __shared__ half_t B0h[4096], B0l[4096], B1h[4096], B1l[4096];
  const int z = blockIdx.z;
  const bool pair = (z < 2);
  const half_t* BRh_g = wh + (pair ? (2 * z) : 4) * 1048576;
  const half_t* BRl_g = wl + (pair ? (2 * z) : 4) * 1048576;
  const half_t* BIh_g = wh + (2 * z + 1) * 1048576;  // pair only
  const half_t* BIl_g = wl + (2 * z + 1) * 1048576;

  const int n0 = blockIdx.x * 128, m0 = blockIdx.y * 128;
  const int tid = threadIdx.x, lane = tid & 63, wid = tid >> 6;
  const int wr = wid >> 1, wc = wid & 1, l15 = lane & 15, l4 = lane >> 4;

  f32x4 accR[4][4], accI[4][4];
#pragma unroll
  for (int i = 0; i < 4; ++i)
#pragma unroll
    for (int j = 0; j < 4; ++j) {
      accR[i][j] = (f32x4){0.f, 0.f, 0.f, 0.f};
      accI[i][j] = (f32x4){0.f, 0.f, 0.f, 0.f};
    }

  const int s0 = wid * 64 + lane, s1 = s0 + 256;
  const int r0 = s0 >> 2, c0 = (s0 & 3) * 8;
  const int r1 = s1 >> 2, c1 = (s1 & 3) * 8;
  half_t* A0 = Ash + wid * 512;   half_t* A1 = Ash + 2048 + wid * 512;
  half_t* La0 = Asl + wid * 512;  half_t* La1 = Asl + 2048 + wid * 512;
  half_t* R0 = B0h + wid * 512;   half_t* R1 = B0h + 2048 + wid * 512;
  half_t* Lr0 = B0l + wid * 512;  half_t* Lr1 = B0l + 2048 + wid * 512;
  half_t* I0 = B1h + wid * 512;   half_t* I1 = B1h + 2048 + wid * 512;
  half_t* Li0 = B1l + wid * 512;  half_t* Li1 = B1l + 2048 + wid * 512;

  for (int k0 = 0; k0 < 1024; k0 += 32) {
    __syncthreads();
    gload16(xh + (m0 + r0) * 1024 + k0 + c0, A0);
    gload16(xh + (m0 + r1) * 1024 + k0 + c1, A1);
    gload16(BRh_g + (n0 + r0) * 1024 + k0 + c0, R0);
    gload16(BRh_g + (n0 + r1) * 1024 + k0 + c1, R1);
    if (pair) {
      gload16(xl + (m0 + r0) * 1024 + k0 + c0, La0);
      gload16(xl + (m0 + r1) * 1024 + k0 + c1, La1);
      gload16(BRl_g + (n0 + r0) * 1024 + k0 + c0, Lr0);
      gload16(BRl_g + (n0 + r1) * 1024 + k0 + c1, Lr1);
      gload16(BIh_g + (n0 + r0) * 1024 + k0 + c0, I0);
      gload16(BIh_g + (n0 + r1) * 1024 + k0 + c1, I1);
      gload16(BIl_g + (n0 + r0) * 1024 + k0 + c0, Li0);
      gload16(BIl_g + (n0 + r1) * 1024 + k0 + c1, Li1);
    }
    __syncthreads();
    f16x8 ah[4], al[4];
#pragma unroll
    for (int i = 0; i < 4; ++i) {
      const int ro = (wr * 64 + i * 16 + l15) * 32 + l4 * 8;
      ah[i] = *(const f16x8*)&Ash[ro];
      if (pair) al[i] = *(const f16x8*)&Asl[ro];
    }
#pragma unroll
    for (int j = 0; j < 4; ++j) {
      const int ro = (wc * 64 + j * 16 + l15) * 32 + l4 * 8;
      const f16x8 bRh = *(const f16x8*)&B0h[ro];
      if (pair) {
        const f16x8 bRl = *(const f16x8*)&B0l[ro];
        const f16x8 bIh = *(const f16x8*)&B1h[ro];
        const f16x8 bIl = *(const f16x8*)&B1l[ro];
#pragma unroll
        for (int i = 0; i < 4; ++i) {
          accR[i][j] = mfma16(ah[i], bRh, accR[i][j]);
          accR[i][j] = mfma16(ah[i], bRl, accR[i][j]);
          accR[i][j] = mfma16(al[i], bRh, accR[i][j]);
          accI[i][j] = mfma16(ah[i], bIh, accI[i][j]);
          accI[i][j] = mfma16(ah[i], bIl, accI[i][j]);
          accI[i][j] = mfma16(al[i], bIh, accI[i][j]);
        }
      } else {
#pragma unroll
        for (int i = 0; i < 4; ++i)
          accR[i][j] = mfma16(ah[i], bRh, accR[i][j]);
      }
    }
  }

  if (pair) {
    half_t* dsth = z ? kbh : qbh;
    half_t* dstl = z ? kbl : qbl;
#pragma unroll
    for (int i = 0; i < 4; ++i) {
      const int mb = m0 + wr * 64 + i * 16 + l4 * 4;
#pragma unroll
      for (int j = 0; j < 4; ++j) {
        const int n = n0 + wc * 64 + j * 16 + l15;
        const int h = n >> 6, d = n & 63;
#pragma unroll
        for (int r = 0; r < 4; ++r) {
          const int m = mb + r;
          const int bq = m >> 11, t = m & 2047;
          const float c = cosb[t * 64 + d], s = sinb[t * 64 + d];
          const float re = accR[i][j][r], im = accI[i][j][r];
          float rer = re * c - im * s;
          float imr = re * s + im * c;
          if (z == 0) { rer *= SCALE_; imr *= SCALE_; }
          const size_t base = ((size_t)(bq * 16 + h) * 2048 + t) * 128;
          half_t hv, lv;
          split2(rer, &hv, &lv); dsth[base + d] = hv;      dstl[base + d] = lv;
          split2(imr, &hv, &lv); dsth[base + 64 + d] = hv; dstl[base + 64 + d] = lv;
        }
      }
    }
  } else {
#pragma unroll
    for (int i = 0; i < 4; ++i) {
      const int mb = m0 + wr * 64 + i * 16 + l4 * 4;
      const int bq = mb >> 11, t = mb & 2047;
#pragma unroll
      for (int j = 0; j < 4; ++j) {
        const int n = n0 + wc * 64 + j * 16 + l15;
        const int hh = n >> 6, d = n & 63;
        f16x4 vh4;
#pragma unroll
        for (int r = 0; r < 4; ++r) vh4[r] = (half_t)accR[i][j][r];
        const size_t off = ((size_t)(bq * 16 + hh) * 64 + d) * 2048 + t;
        *(f16x4*)&vTh[off] = vh4;
      }
    }
  }
}

// ---------------------------------------------------------------------------
// Flash attention, split-fp16 QK (3-term), hi-only PV. 512 thr (8 waves);
// QB=128 (wave w owns rows q0+w*16..+15), KB=32, D'=128, Dv=64.
// Single barrier per k-tile; dbuf K(hi/lo)/V(hi) via global_load_lds with
// pre-swizzled global source; P (hi) LDS wave-private. LDS 48KB.
// Grid 512: bh=i&31 (XCD locality); qt paired so per-CU work is uniform.
// ---------------------------------------------------------------------------
__global__ __launch_bounds__(512) void attn_kernel(
    const half_t* __restrict__ qbh, const half_t* __restrict__ qbl,
    const half_t* __restrict__ kbh, const half_t* __restrict__ kbl,
    const half_t* __restrict__ vTh,
    half_t* __restrict__ abh, half_t* __restrict__ abl)
{
  const int i = blockIdx.x;                 // 0..511
  const int bh = i & 31;
  const int idx = (i >> 5) & 7;
  const int qt = (i < 256) ? (15 - idx) : idx;
  const int b = bh >> 4, h = bh & 15;
  const int tid = threadIdx.x, lane = tid & 63, w = tid >> 6;
  const int l15 = lane & 15, l4 = lane >> 4;
  const int q0 = qt * 128;

  __shared__ half_t Kh[2][4096], Kl[2][4096];  // [32 t][128 d] per buf (32KB)
  __shared__ half_t Vh[2][2048];               // [64 d][32 t] per buf (8KB)
  __shared__ half_t Ph[4096];                  // [128 q][32 k]       (8KB)

  f16x8 qh[4], ql[4];
  {
    const size_t qoff = ((size_t)bh * 2048 + q0 + w * 16 + l15) * 128;
#pragma unroll
    for (int c = 0; c < 4; ++c) {
      qh[c] = *(const f16x8*)(qbh + qoff + c * 32 + l4 * 8);
      ql[c] = *(const f16x8*)(qbl + qoff + c * 32 + l4 * 8);
    }
  }

  f32x4 o[4];
#pragma unroll
  for (int n = 0; n < 4; ++n) o[n] = (f32x4){0.f, 0.f, 0.f, 0.f};
  float mrow[4] = {-3e38f, -3e38f, -3e38f, -3e38f};
  float lrow[4] = {0.f, 0.f, 0.f, 0.f};

  const half_t* kh_p = kbh + (size_t)bh * 2048 * 128;
  const half_t* kl_p = kbl + (size_t)bh * 2048 * 128;
  const half_t* vh_p = vTh + (size_t)bh * 64 * 2048;

  // K: 512 16B-slots/tile; LDS slot = w*64+lane (linear); global pre-swizzled.
  const int krow = w * 4 + (lane >> 4);               // 0..31
  const int ks = lane & 15;
  const int kg = (ks & 8) | ((ks & 7) ^ (krow & 7));  // involution
  // V: 256 slots/tile, waves 0-3.
  const int vrow = (w & 3) * 16 + (lane >> 2);        // 0..63
  const int vs = lane & 3;
  const int vg = vs ^ ((vrow >> 1) & 3);              // involution

  const int nkt = 4 * (qt + 1);
  const int qminw = q0 + w * 16, qmaxw = qminw + 15;

  // prologue: stage tile 0 into buf 0
  gload16(kh_p + krow * 128 + kg * 8, &Kh[0][w * 512]);
  gload16(kl_p + krow * 128 + kg * 8, &Kl[0][w * 512]);
  if (w < 4) gload16(vh_p + vrow * 2048 + vg * 8, &Vh[0][(w & 3) * 512]);

  for (int kt = 0; kt < nkt; ++kt) {
    const int k0 = kt * 32;
    const int cb = kt & 1;
    __syncthreads();  // tile-kt loads landed; all waves done with buf cb^1

    // prefetch tile kt+1 (clamped) into the other buffer
    {
      const int k0n = (kt + 1 < nkt) ? k0 + 32 : 0;
      const int nb = cb ^ 1;
      gload16(kh_p + (k0n + krow) * 128 + kg * 8, &Kh[nb][w * 512]);
      gload16(kl_p + (k0n + krow) * 128 + kg * 8, &Kl[nb][w * 512]);
      if (w < 4) gload16(vh_p + vrow * 2048 + k0n + vg * 8, &Vh[nb][(w & 3) * 512]);
    }

    if (k0 > qmaxw) continue;  // fully masked for this wave

    // S = Q K^T, 3-term split
    f32x4 s[2];
    s[0] = (f32x4){0.f, 0.f, 0.f, 0.f};
    s[1] = (f32x4){0.f, 0.f, 0.f, 0.f};
#pragma unroll
    for (int c = 0; c < 4; ++c) {
#pragma unroll
      for (int n = 0; n < 2; ++n) {
        const int row = n * 16 + l15;
        const int co = c * 4 + l4;
        const int sr = (co & 8) | ((co & 7) ^ (row & 7));
        const f16x8 kfh = *(const f16x8*)&Kh[cb][row * 128 + sr * 8];
        const f16x8 kfl = *(const f16x8*)&Kl[cb][row * 128 + sr * 8];
        s[n] = mfma16(qh[c], kfh, s[n]);
        s[n] = mfma16(qh[c], kfl, s[n]);
        s[n] = mfma16(ql[c], kfh, s[n]);
      }
    }

    if (k0 + 31 > qminw) {  // partial tile: elementwise causal mask
#pragma unroll
      for (int n = 0; n < 2; ++n)
#pragma unroll
        for (int r = 0; r < 4; ++r)
          if (k0 + n * 16 + l15 > qminw + l4 * 4 + r) s[n][r] = -3e38f;
    }

    // online softmax (row groups = 16 contiguous lanes)
#pragma unroll
    for (int r = 0; r < 4; ++r) {
      float mx = fmaxf(s[0][r], s[1][r]);
      mx = fmaxf(mx, __shfl_xor(mx, 1));
      mx = fmaxf(mx, __shfl_xor(mx, 2));
      mx = fmaxf(mx, __shfl_xor(mx, 4));
      mx = fmaxf(mx, __shfl_xor(mx, 8));
      const float mnew = fmaxf(mrow[r], mx);
      const float alpha = __expf(mrow[r] - mnew);
      const float p0 = __expf(s[0][r] - mnew);
      const float p1 = __expf(s[1][r] - mnew);
      float rs = p0 + p1;
      rs += __shfl_xor(rs, 1);
      rs += __shfl_xor(rs, 2);
      rs += __shfl_xor(rs, 4);
      rs += __shfl_xor(rs, 8);
      lrow[r] = lrow[r] * alpha + rs;
      mrow[r] = mnew;
#pragma unroll
      for (int n = 0; n < 4; ++n) o[n][r] *= alpha;
      const int prow = w * 16 + l4 * 4 + r;
      const int psw = (prow >> 2) & 3;
      {
        const int col = l15, sp = (col >> 3) ^ psw;
        Ph[prow * 32 + sp * 8 + (col & 7)] = (half_t)p0;
      }
      {
        const int col = 16 + l15, sp = (col >> 3) ^ psw;
        Ph[prow * 32 + sp * 8 + (col & 7)] = (half_t)p1;
      }
    }

    // O += P V (hi-only; P rows wave-private, no barrier)
    {
      const int prow = w * 16 + l15;
      const int spp = l4 ^ ((prow >> 2) & 3);
      const f16x8 pfh = *(const f16x8*)&Ph[prow * 32 + spp * 8];
#pragma unroll
      for (int n = 0; n < 4; ++n) {
        const int vr = n * 16 + l15;
        const int sv = l4 ^ ((vr >> 1) & 3);
        const f16x8 vfh = *(const f16x8*)&Vh[cb][vr * 32 + sv * 8];
        o[n] = mfma16(pfh, vfh, o[n]);
      }
    }
  }

  const int mg = b * 2048 + q0 + w * 16 + l4 * 4;
#pragma unroll
  for (int r = 0; r < 4; ++r) {
    const float inv = 1.0f / lrow[r];
    const int m = mg + r;
#pragma unroll
    for (int n = 0; n < 4; ++n) {
      half_t hv, lv; split2(o[n][r] * inv, &hv, &lv);
      abh[m * 1024 + h * 64 + n * 16 + l15] = hv;
      abl[m * 1024 + h * 64 + n * 16 + l15] = lv;
    }
  }
}

// ---------------------------------------------------------------------------
// Output projection: abuf (hi/lo) @ Wo (hi/lo, 3-term) -> fp32 d_out.
// ---------------------------------------------------------------------------
__global__ __launch_bounds__(256) void outproj_kernel(
    const half_t* __restrict__ Agh, const half_t* __restrict__ Agl,
    const half_t* __restrict__ wh, const half_t* __restrict__ wl,
    float* __restrict__ outp)
{
  __shared__ half_t Ash[4096], Asl[4096], Bsh[4096], Bsl[4096];
  const half_t* Bth = wh + 5 * 1048576;
  const half_t* Btl = wl + 5 * 1048576;

  const int n0 = blockIdx.x * 128, m0 = blockIdx.y * 128;
  const int tid = threadIdx.x, lane = tid & 63, wid = tid >> 6;
  const int wr = wid >> 1, wc = wid & 1, l15 = lane & 15, l4 = lane >> 4;

  f32x4 acc[4][4];
#pragma unroll
  for (int i = 0; i < 4; ++i)
#pragma unroll
    for (int j = 0; j < 4; ++j) acc[i][j] = (f32x4){0.f, 0.f, 0.f, 0.f};

  const int s0 = wid * 64 + lane, s1 = s0 + 256;
  const int r0 = s0 >> 2, c0 = (s0 & 3) * 8;
  const int r1 = s1 >> 2, c1 = (s1 & 3) * 8;
  half_t* Ah0 = Ash + wid * 512;        half_t* Ah1 = Ash + 2048 + wid * 512;
  half_t* Al0 = Asl + wid * 512;        half_t* Al1 = Asl + 2048 + wid * 512;
  half_t* Bh0 = Bsh + wid * 512;        half_t* Bh1 = Bsh + 2048 + wid * 512;
  half_t* Bl0 = Bsl + wid * 512;        half_t* Bl1 = Bsl + 2048 + wid * 512;

  for (int k0 = 0; k0 < 1024; k0 += 32) {
    __syncthreads();
    gload16(Agh + (m0 + r0) * 1024 + k0 + c0, Ah0);
    gload16(Agh + (m0 + r1) * 1024 + k0 + c1, Ah1);
    gload16(Agl + (m0 + r0) * 1024 + k0 + c0, Al0);
    gload16(Agl + (m0 + r1) * 1024 + k0 + c1, Al1);
    gload16(Bth + (n0 + r0) * 1024 + k0 + c0, Bh0);
    gload16(Bth + (n0 + r1) * 1024 + k0 + c1, Bh1);
    gload16(Btl + (n0 + r0) * 1024 + k0 + c0, Bl0);
    gload16(Btl + (n0 + r1) * 1024 + k0 + c1, Bl1);
    __syncthreads();
    f16x8 ah[4], al[4], bh[4], bl[4];
#pragma unroll
    for (int i = 0; i < 4; ++i) {
      const int ro = (wr * 64 + i * 16 + l15) * 32 + l4 * 8;
      ah[i] = *(const f16x8*)&Ash[ro];
      al[i] = *(const f16x8*)&Asl[ro];
    }
#pragma unroll
    for (int j = 0; j < 4; ++j) {
      const int ro = (wc * 64 + j * 16 + l15) * 32 + l4 * 8;
      bh[j] = *(const f16x8*)&Bsh[ro];
      bl[j] = *(const f16x8*)&Bsl[ro];
    }
#pragma unroll
    for (int i = 0; i < 4; ++i)
#pragma unroll
      for (int j = 0; j < 4; ++j) {
        acc[i][j] = mfma16(ah[i], bh[j], acc[i][j]);
        acc[i][j] = mfma16(ah[i], bl[j], acc[i][j]);
        acc[i][j] = mfma16(al[i], bh[j], acc[i][j]);
      }
  }

#pragma unroll
  for (int i = 0; i < 4; ++i) {
    const int mb = m0 + wr * 64 + i * 16 + l4 * 4;
#pragma unroll
    for (int j = 0; j < 4; ++j) {
      const int n = n0 + wc * 64 + j * 16 + l15;
#pragma unroll
      for (int r = 0; r < 4; ++r) outp[(mb + r) * 1024 + n] = acc[i][j][r];
    }
  }
}

// ---------------------------------------------------------------------------
extern "C" void kernel_launch(void* const* d_in, const int* in_sizes, int n_in,
                              void* d_out, int out_size, void* d_ws,
                              size_t ws_size, hipStream_t stream) {
  const float* x    = (const float*)d_in[0];
  const float* Wqre = (const float*)d_in[1];
  const float* Wqim = (const float*)d_in[2];
  const float* Wkre = (const float*)d_in[3];
  const float* Wkim = (const float*)d_in[4];
  const float* Wv   = (const float*)d_in[5];
  const float* Wo   = (const float*)d_in[6];
  const float* cosb = (const float*)d_in[7];
  const float* sinb = (const float*)d_in[8];

  char* w = (char*)d_ws;
  const size_t MB = (size_t)1 << 20;
  half_t* wh6 = (half_t*)(w + 0 * MB);    // 12 MB: 6x [1024][1024] fp16 hi
  half_t* wl6 = (half_t*)(w + 12 * MB);   // 12 MB: lo
  half_t* xh  = (half_t*)(w + 24 * MB);   // 8 MB
  half_t* xl  = (half_t*)(w + 32 * MB);   // 8 MB
  half_t* qbh = (half_t*)(w + 40 * MB);   // 16 MB [32][2048][128]
  half_t* qbl = (half_t*)(w + 56 * MB);   // 16 MB
  half_t* kbh = (half_t*)(w + 72 * MB);   // 16 MB
  half_t* kbl = (half_t*)(w + 88 * MB);   // 16 MB
  half_t* vTh = (half_t*)(w + 104 * MB);  // 8 MB [32][64][2048]
  half_t* abh = (half_t*)(w + 112 * MB);  // 8 MB [4096][1024]
  half_t* abl = (half_t*)(w + 120 * MB);  // 8 MB  (total 128 MB)

  dim3 blk(256);
  convw_kernel<<<dim3(32, 32, 6), blk, 0, stream>>>(Wqre, Wqim, Wkre, Wkim, Wv,
                                                    Wo, wh6, wl6);
  convx_kernel<<<dim3(4096), blk, 0, stream>>>(x, xh, xl);
  proj_pair_kernel<<<dim3(8, 32, 3), blk, 0, stream>>>(
      xh, xl, wh6, wl6, cosb, sinb, qbh, qbl, kbh, kbl, vTh);
  attn_kernel<<<dim3(512), dim3(512), 0, stream>>>(qbh, qbl, kbh, kbl, vTh,
                                                   abh, abl);
  outproj_kernel<<<dim3(8, 32), blk, 0, stream>>>(abh, abl, wh6, wl6,
                                                  (float*)d_out);
}